// Round 2
// baseline (240.695 us; speedup 1.0000x reference)
//
#include <hip/hip_runtime.h>
#include <math.h>

// ---------- types ----------
typedef __bf16 bf16_t;
typedef __bf16 bf16x8 __attribute__((ext_vector_type(8)));
typedef __bf16 bf16x4 __attribute__((ext_vector_type(4)));
typedef float  f32x4  __attribute__((ext_vector_type(4)));

#define MFMA16(a, b, c) __builtin_amdgcn_mfma_f32_16x16x32_bf16((a), (b), (c), 0, 0, 0)

// B=2, N=M=2048, QUERY_DIM=CONTEXT_DIM=1024, HEADS=8, DIM_HEAD=64, INNER=512
#define INNER   512
#define DHEAD   64
// SCALE * log2(e): Q is pre-scaled so softmax runs in exp2 domain (native v_exp_f32)
#define QSCALE  0.18033688f

// ---------- fp32 -> bf16 convert, x and context fused ----------
__global__ __launch_bounds__(256) void cvt_k(const float* __restrict__ x,
                                             const float* __restrict__ ctx,
                                             bf16_t* __restrict__ xb,
                                             bf16_t* __restrict__ cb) {
  const float* in = blockIdx.y ? ctx : x;
  bf16_t* out     = blockIdx.y ? cb  : xb;
  int i = blockIdx.x * 256 + threadIdx.x;   // 1048576 float4 per tensor
  float4 f = ((const float4*)in)[i];
  bf16x4 v = { (bf16_t)f.x, (bf16_t)f.y, (bf16_t)f.z, (bf16_t)f.w };
  ((bf16x4*)out)[i] = v;
}

// ---------- weight transpose+convert: W[K][N] f32 -> WT[N][K] bf16 ----------
__global__ __launch_bounds__(256) void wtrans_k(const float* __restrict__ Wq,
                                                const float* __restrict__ Wk,
                                                const float* __restrict__ Wv,
                                                const float* __restrict__ Wo,
                                                bf16_t* __restrict__ WqT,
                                                bf16_t* __restrict__ WkT,
                                                bf16_t* __restrict__ WvT,
                                                bf16_t* __restrict__ WoT) {
  int z = blockIdx.y;
  const float* W; bf16_t* WT; int K, N;
  if (z == 0)      { W = Wq; WT = WqT; K = 1024; N = 512; }
  else if (z == 1) { W = Wk; WT = WkT; K = 1024; N = 512; }
  else if (z == 2) { W = Wv; WT = WvT; K = 1024; N = 512; }
  else             { W = Wo; WT = WoT; K = 512;  N = 1024; }
  int tK = K >> 6;
  int bid = blockIdx.x;
  int kt = bid % tK, nt = bid / tK;
  int k0 = kt << 6, n0 = nt << 6;
  __shared__ float tile[64][65];
  for (int idx = threadIdx.x; idx < 4096; idx += 256) {
    int r = idx >> 6, c = idx & 63;
    tile[r][c] = W[(size_t)(k0 + r) * N + n0 + c];
  }
  __syncthreads();
  for (int idx = threadIdx.x; idx < 4096; idx += 256) {
    int r = idx >> 6, c = idx & 63;
    WT[(size_t)(n0 + r) * K + k0 + c] = (bf16_t)tile[c][r];
  }
}

// ---------- V transpose: Vb[4096][512] bf16 -> Vt[bh=16][d=64][key=2048] ----------
__global__ __launch_bounds__(256) void vtrans_k(const bf16_t* __restrict__ Vb,
                                                bf16_t* __restrict__ Vt) {
  int m0 = blockIdx.x << 6;
  int bh = blockIdx.y;
  int b = bh >> 3, h = bh & 7;
  __shared__ bf16_t tile[64][65];
  for (int idx = threadIdx.x; idx < 4096; idx += 256) {
    int r = idx >> 6, c = idx & 63;
    tile[r][c] = Vb[(size_t)(b * 2048 + m0 + r) * INNER + h * DHEAD + c];
  }
  __syncthreads();
  for (int idx = threadIdx.x; idx < 4096; idx += 256) {
    int r = idx >> 6, c = idx & 63;
    Vt[((size_t)bh * 64 + r) * 2048 + m0 + c] = tile[c][r];
  }
}

// ---------- 128x128 GEMM core: C = A[M][K] @ Bt[N][K]^T ----------
__device__ __forceinline__ void gemm128(const bf16_t* __restrict__ A,
                                        const bf16_t* __restrict__ Bt,
                                        int K, int N, int row0, int n0, float scale,
                                        bf16_t* __restrict__ Cb, float* __restrict__ Cf,
                                        const float* __restrict__ bias) {
  __shared__ bf16_t As[128 * 40];
  __shared__ bf16_t Bs[128 * 40];
  const int tid = threadIdx.x;
  const int w = tid >> 6, lane = tid & 63, quad = lane >> 4, l16 = lane & 15;
  const int sr = tid >> 2, sc = (tid & 3) << 3;
  const bf16_t* ga = A  + (size_t)(row0 + sr) * K + sc;
  const bf16_t* gb = Bt + (size_t)(n0  + sr) * K + sc;

  f32x4 acc[4][4];
#pragma unroll
  for (int i = 0; i < 4; ++i)
#pragma unroll
    for (int j = 0; j < 4; ++j) acc[i][j] = f32x4{0.f, 0.f, 0.f, 0.f};

  int4 ra0 = *(const int4*)(ga);
  int4 ra1 = *(const int4*)(ga + (size_t)64 * K);
  int4 rb0 = *(const int4*)(gb);
  int4 rb1 = *(const int4*)(gb + (size_t)64 * K);

  const int mrow = (w & 1) << 6, ncol = (w >> 1) << 6;
  const int KT = K >> 5;
  for (int kt = 0; kt < KT; ++kt) {
    __syncthreads();
    *(int4*)&As[sr * 40 + sc]        = ra0;
    *(int4*)&As[(sr + 64) * 40 + sc] = ra1;
    *(int4*)&Bs[sr * 40 + sc]        = rb0;
    *(int4*)&Bs[(sr + 64) * 40 + sc] = rb1;
    __syncthreads();
    if (kt + 1 < KT) {
      int k0 = (kt + 1) << 5;
      ra0 = *(const int4*)(ga + k0);
      ra1 = *(const int4*)(ga + (size_t)64 * K + k0);
      rb0 = *(const int4*)(gb + k0);
      rb1 = *(const int4*)(gb + (size_t)64 * K + k0);
    }
    bf16x8 af[4], bfr[4];
#pragma unroll
    for (int i = 0; i < 4; ++i)
      af[i] = *(const bf16x8*)&As[(mrow + i * 16 + l16) * 40 + quad * 8];
#pragma unroll
    for (int j = 0; j < 4; ++j)
      bfr[j] = *(const bf16x8*)&Bs[(ncol + j * 16 + l16) * 40 + quad * 8];
#pragma unroll
    for (int i = 0; i < 4; ++i)
#pragma unroll
      for (int j = 0; j < 4; ++j)
        acc[i][j] = MFMA16(af[i], bfr[j], acc[i][j]);
  }
#pragma unroll
  for (int i = 0; i < 4; ++i) {
    int row = row0 + mrow + i * 16 + quad * 4;
#pragma unroll
    for (int j = 0; j < 4; ++j) {
      int col = n0 + ncol + j * 16 + l16;
#pragma unroll
      for (int r = 0; r < 4; ++r) {
        if (Cf) Cf[(size_t)(row + r) * N + col] = acc[i][j][r] + bias[col];
        else    Cb[(size_t)(row + r) * N + col] = (bf16_t)(acc[i][j][r] * scale);
      }
    }
  }
}

__global__ __launch_bounds__(256, 2) void gemm_qkv_k(const bf16_t* __restrict__ xb,
                                                     const bf16_t* __restrict__ cb,
                                                     const bf16_t* __restrict__ WqT,
                                                     const bf16_t* __restrict__ WkT,
                                                     const bf16_t* __restrict__ WvT,
                                                     bf16_t* __restrict__ Qb,
                                                     bf16_t* __restrict__ Kb,
                                                     bf16_t* __restrict__ Vb) {
  int z = blockIdx.z;
  const bf16_t* A  = (z == 0) ? xb : cb;
  const bf16_t* Bt = (z == 0) ? WqT : (z == 1) ? WkT : WvT;
  bf16_t* C        = (z == 0) ? Qb  : (z == 1) ? Kb  : Vb;
  float scale      = (z == 0) ? QSCALE : 1.0f;   // fold 1/8 * log2(e) into Q
  gemm128(A, Bt, 1024, 512, blockIdx.y * 128, blockIdx.x * 128, scale, C, nullptr, nullptr);
}

__global__ __launch_bounds__(256, 2) void gemm_out_k(const bf16_t* __restrict__ AO,
                                                     const bf16_t* __restrict__ WoT,
                                                     const float* __restrict__ bo,
                                                     float* __restrict__ out) {
  gemm128(AO, WoT, 512, 1024, blockIdx.y * 128, blockIdx.x * 128, 1.0f, nullptr, out, bo);
}

// ---------- flash attention, transposed-S formulation ----------
// Per block: 64 q-rows, 4 waves, each wave owns 16 q-columns.
// S^T = K · Q^T  (C-layout: col=l16=q, row=quad*4+r=key) -> per-lane scalar softmax
// state, local reg reductions + 2+2 shuffles per 128-key tile.
// O^T = Vt · P^T accumulated in registers; epilogue transposes via LDS.
__global__ __launch_bounds__(256, 2) void attn_k(const bf16_t* __restrict__ Qb,
                                                 const bf16_t* __restrict__ Kb,
                                                 const bf16_t* __restrict__ Vt,
                                                 bf16_t* __restrict__ AO) {
  const int tid = threadIdx.x;
  const int w = tid >> 6, lane = tid & 63, quad = lane >> 4, l16 = lane & 15;
  const int qt = blockIdx.x;        // 0..31
  const int bh = blockIdx.y;        // 0..15
  const int b = bh >> 3, h = bh & 7;

  __shared__ bf16_t Ks[128 * 72];   // [key][d]   stride 72
  __shared__ bf16_t Vs[64 * 136];   // [d][key]   stride 136
  __shared__ bf16_t Ps[64 * 136];   // [q][key]   stride 136 (wave-private rows)

  // Q B-frags: B^T[n=q][k=d] = Q rows (Q pre-scaled by 1/8*log2e)
  const int qrow = b * 2048 + qt * 64 + w * 16 + l16;
  const bf16_t* qptr = Qb + (size_t)qrow * INNER + h * DHEAD;
  bf16x8 bq[2];
  bq[0] = *(const bf16x8*)(qptr + quad * 8);
  bq[1] = *(const bf16x8*)(qptr + 32 + quad * 8);

  f32x4 o[4];
#pragma unroll
  for (int dt = 0; dt < 4; ++dt) o[dt] = f32x4{0.f, 0.f, 0.f, 0.f};
  float m_s = -__builtin_inff(), l_s = 0.f;

  const bf16_t* kbase  = Kb + ((size_t)b * 2048) * INNER + h * DHEAD;
  const bf16_t* vtbase = Vt + ((size_t)bh * 64) * 2048;

  // staging maps: Ks 128x64 (4 int4/thread), Vs 64x128 (4 int4/thread)
  const int ksr = tid >> 3, ksc = (tid & 7) << 3;
  const int vsr = tid >> 4, vsc = (tid & 15) << 3;

  int4 ka[4], va[4];
#pragma unroll
  for (int p = 0; p < 4; ++p) {
    ka[p] = *(const int4*)(kbase + (size_t)(ksr + 32 * p) * INNER + ksc);
    va[p] = *(const int4*)(vtbase + (size_t)(vsr + 16 * p) * 2048 + vsc);
  }

  for (int kt = 0; kt < 16; ++kt) {
    __syncthreads();                 // previous iteration's LDS reads done
#pragma unroll
    for (int p = 0; p < 4; ++p) {
      *(int4*)&Ks[(ksr + 32 * p) * 72 + ksc]  = ka[p];
      *(int4*)&Vs[(vsr + 16 * p) * 136 + vsc] = va[p];
    }
    __syncthreads();
    if (kt + 1 < 16) {               // prefetch next tile into registers
      int k0 = (kt + 1) * 128;
#pragma unroll
      for (int p = 0; p < 4; ++p) {
        ka[p] = *(const int4*)(kbase + (size_t)(k0 + ksr + 32 * p) * INNER + ksc);
        va[p] = *(const int4*)(vtbase + (size_t)(vsr + 16 * p) * 2048 + k0 + vsc);
      }
    }

    // S^T tile [128 keys][16 q] per wave
    f32x4 s[8];
#pragma unroll
    for (int jt = 0; jt < 8; ++jt) s[jt] = f32x4{0.f, 0.f, 0.f, 0.f};
#pragma unroll
    for (int jt = 0; jt < 8; ++jt) {
#pragma unroll
      for (int ks = 0; ks < 2; ++ks) {
        bf16x8 ak = *(const bf16x8*)&Ks[(jt * 16 + l16) * 72 + ks * 32 + quad * 8];
        s[jt] = MFMA16(ak, bq[ks], s[jt]);
      }
    }

    // online softmax (exp2 domain), per-lane scalar state for q-col l16
    float mx = -__builtin_inff();
#pragma unroll
    for (int jt = 0; jt < 8; ++jt) {
      float a = fmaxf(fmaxf(s[jt][0], s[jt][1]), fmaxf(s[jt][2], s[jt][3]));
      mx = fmaxf(mx, a);
    }
    mx = fmaxf(mx, __shfl_xor(mx, 16, 64));
    mx = fmaxf(mx, __shfl_xor(mx, 32, 64));
    float mnew = fmaxf(m_s, mx);
    float alpha = __builtin_amdgcn_exp2f(m_s - mnew);
    float rs = 0.f;
#pragma unroll
    for (int jt = 0; jt < 8; ++jt) {
#pragma unroll
      for (int r = 0; r < 4; ++r) {
        float p = __builtin_amdgcn_exp2f(s[jt][r] - mnew);
        s[jt][r] = p;
        rs += p;
      }
    }
    rs += __shfl_xor(rs, 16, 64);
    rs += __shfl_xor(rs, 32, 64);
    l_s = l_s * alpha + rs;
    m_s = mnew;
#pragma unroll
    for (int dt = 0; dt < 4; ++dt) o[dt] *= alpha;

    // P^T (C-layout) -> Ps[q][key] (wave-private rows, packed b64 writes)
#pragma unroll
    for (int jt = 0; jt < 8; ++jt) {
      bf16x4 pk = { (bf16_t)s[jt][0], (bf16_t)s[jt][1],
                    (bf16_t)s[jt][2], (bf16_t)s[jt][3] };
      *(bf16x4*)&Ps[(w * 16 + l16) * 136 + jt * 16 + quad * 4] = pk;
    }

    // O^T += Vt · P^T
#pragma unroll
    for (int kc = 0; kc < 4; ++kc) {
      bf16x8 bp = *(const bf16x8*)&Ps[(w * 16 + l16) * 136 + kc * 32 + quad * 8];
#pragma unroll
      for (int dt = 0; dt < 4; ++dt) {
        bf16x8 av = *(const bf16x8*)&Vs[(dt * 16 + l16) * 136 + kc * 32 + quad * 8];
        o[dt] = MFMA16(av, bp, o[dt]);
      }
    }
  }

  // epilogue: O^T[d][q] -> LDS [q][d] -> coalesced global stores
  __syncthreads();                   // all waves done reading Ks
  float inv = 1.0f / l_s;
#pragma unroll
  for (int dt = 0; dt < 4; ++dt) {
    bf16x4 ov = { (bf16_t)(o[dt][0] * inv), (bf16_t)(o[dt][1] * inv),
                  (bf16_t)(o[dt][2] * inv), (bf16_t)(o[dt][3] * inv) };
    *(bf16x4*)&Ks[(w * 16 + l16) * 72 + dt * 16 + quad * 4] = ov;
  }
  __syncthreads();
  {
    int sr = tid >> 2, sc = (tid & 3) << 4;
    int4 r0 = *(const int4*)&Ks[sr * 72 + sc];
    int4 r1 = *(const int4*)&Ks[sr * 72 + sc + 8];
    bf16_t* aout = AO + ((size_t)(b * 2048 + qt * 64 + sr)) * INNER + h * DHEAD + sc;
    *(int4*)aout       = r0;
    *(int4*)(aout + 8) = r1;
  }
}

// ---------- launch ----------
extern "C" void kernel_launch(void* const* d_in, const int* in_sizes, int n_in,
                              void* d_out, int out_size, void* d_ws, size_t ws_size,
                              hipStream_t stream) {
  const float* x   = (const float*)d_in[0];
  const float* ctx = (const float*)d_in[1];
  const float* Wq  = (const float*)d_in[2];
  const float* Wk  = (const float*)d_in[3];
  const float* Wv  = (const float*)d_in[4];
  const float* Wo  = (const float*)d_in[5];
  const float* bo  = (const float*)d_in[6];
  float* out = (float*)d_out;

  char* ws = (char*)d_ws;
  bf16_t* xb  = (bf16_t*)(ws + 0);          //  8 MB  [4096][1024]
  bf16_t* cb  = (bf16_t*)(ws + 8388608);    //  8 MB  [4096][1024]
  bf16_t* WqT = (bf16_t*)(ws + 16777216);   //  1 MB  [512][1024]
  bf16_t* WkT = (bf16_t*)(ws + 17825792);   //  1 MB
  bf16_t* WvT = (bf16_t*)(ws + 18874368);   //  1 MB
  bf16_t* WoT = (bf16_t*)(ws + 19922944);   //  1 MB  [1024][512]
  bf16_t* Qb  = (bf16_t*)(ws + 20971520);   //  4 MB  [4096][512] (pre-scaled)
  bf16_t* Kb  = (bf16_t*)(ws + 25165824);   //  4 MB
  bf16_t* Vb  = (bf16_t*)(ws + 29360128);   //  4 MB
  bf16_t* Vt  = (bf16_t*)(ws + 33554432);   //  4 MB  [16][64][2048]
  bf16_t* AO  = (bf16_t*)(ws + 37748736);   //  4 MB  [4096][512]

  cvt_k<<<dim3(4096, 2), 256, 0, stream>>>(x, ctx, xb, cb);
  wtrans_k<<<dim3(128, 4), 256, 0, stream>>>(Wq, Wk, Wv, Wo, WqT, WkT, WvT, WoT);
  gemm_qkv_k<<<dim3(4, 32, 3), 256, 0, stream>>>(xb, cb, WqT, WkT, WvT, Qb, Kb, Vb);
  vtrans_k<<<dim3(32, 16), 256, 0, stream>>>(Vb, Vt);
  attn_k<<<dim3(32, 16), 256, 0, stream>>>(Qb, Kb, Vt, AO);
  gemm_out_k<<<dim3(8, 32), 256, 0, stream>>>(AO, WoT, bo, out);
}

// Round 3
// 184.738 us; speedup vs baseline: 1.3029x; 1.3029x over previous
//
#include <hip/hip_runtime.h>
#include <math.h>

// ---------- types ----------
typedef __bf16 bf16_t;
typedef __bf16 bf16x8 __attribute__((ext_vector_type(8)));
typedef __bf16 bf16x4 __attribute__((ext_vector_type(4)));
typedef float  f32x4  __attribute__((ext_vector_type(4)));

#define MFMA16(a, b, c) __builtin_amdgcn_mfma_f32_16x16x32_bf16((a), (b), (c), 0, 0, 0)

// B=2, N=M=2048, QUERY_DIM=CONTEXT_DIM=1024, HEADS=8, DIM_HEAD=64, INNER=512
#define INNER   512
#define DHEAD   64
// SCALE * log2(e): Q pre-scaled so softmax runs in exp2 domain
#define QSCALE  0.18033688f

// direct HBM -> LDS, 16 B per lane; LDS dest = wave-uniform base + lane*16
__device__ __forceinline__ void g2l(const bf16_t* g, bf16_t* l) {
  __builtin_amdgcn_global_load_lds(
      (const __attribute__((address_space(1))) unsigned int*)g,
      (__attribute__((address_space(3))) unsigned int*)l, 16, 0, 0);
}

// ---------- fp32 -> bf16 convert, x and context fused ----------
__global__ __launch_bounds__(256) void cvt_k(const float* __restrict__ x,
                                             const float* __restrict__ ctx,
                                             bf16_t* __restrict__ xb,
                                             bf16_t* __restrict__ cb) {
  const float* in = blockIdx.y ? ctx : x;
  bf16_t* out     = blockIdx.y ? cb  : xb;
  int i = blockIdx.x * 256 + threadIdx.x;
  float4 f = ((const float4*)in)[i];
  bf16x4 v = { (bf16_t)f.x, (bf16_t)f.y, (bf16_t)f.z, (bf16_t)f.w };
  ((bf16x4*)out)[i] = v;
}

// ---------- weight transpose+convert: W[K][N] f32 -> WT[N][K] bf16 ----------
__global__ __launch_bounds__(256) void wtrans_k(const float* __restrict__ Wq,
                                                const float* __restrict__ Wk,
                                                const float* __restrict__ Wv,
                                                const float* __restrict__ Wo,
                                                bf16_t* __restrict__ WqT,
                                                bf16_t* __restrict__ WkT,
                                                bf16_t* __restrict__ WvT,
                                                bf16_t* __restrict__ WoT) {
  int z = blockIdx.y;
  const float* W; bf16_t* WT; int K, N;
  if (z == 0)      { W = Wq; WT = WqT; K = 1024; N = 512; }
  else if (z == 1) { W = Wk; WT = WkT; K = 1024; N = 512; }
  else if (z == 2) { W = Wv; WT = WvT; K = 1024; N = 512; }
  else             { W = Wo; WT = WoT; K = 512;  N = 1024; }
  int tK = K >> 6;
  int bid = blockIdx.x;
  int kt = bid % tK, nt = bid / tK;
  int k0 = kt << 6, n0 = nt << 6;
  __shared__ float tile[64][65];
  for (int idx = threadIdx.x; idx < 4096; idx += 256) {
    int r = idx >> 6, c = idx & 63;
    tile[r][c] = W[(size_t)(k0 + r) * N + n0 + c];
  }
  __syncthreads();
  for (int idx = threadIdx.x; idx < 4096; idx += 256) {
    int r = idx >> 6, c = idx & 63;
    WT[(size_t)(n0 + r) * K + k0 + c] = (bf16_t)tile[c][r];
  }
}

// ---------- V transpose: Vb[4096][512] bf16 -> Vt[bh=16][d=64][key=2048] ----------
__global__ __launch_bounds__(256) void vtrans_k(const bf16_t* __restrict__ Vb,
                                                bf16_t* __restrict__ Vt) {
  int m0 = blockIdx.x << 6;
  int bh = blockIdx.y;
  int b = bh >> 3, h = bh & 7;
  __shared__ bf16_t tile[64][65];
  for (int idx = threadIdx.x; idx < 4096; idx += 256) {
    int r = idx >> 6, c = idx & 63;
    tile[r][c] = Vb[(size_t)(b * 2048 + m0 + r) * INNER + h * DHEAD + c];
  }
  __syncthreads();
  for (int idx = threadIdx.x; idx < 4096; idx += 256) {
    int r = idx >> 6, c = idx & 63;
    Vt[((size_t)bh * 64 + r) * 2048 + m0 + c] = tile[c][r];
  }
}

// ---------- 128x128 GEMM core: C = A[M][K] @ Bt[N][K]^T ----------
__device__ __forceinline__ void gemm128(const bf16_t* __restrict__ A,
                                        const bf16_t* __restrict__ Bt,
                                        int K, int N, int row0, int n0, float scale,
                                        bf16_t* __restrict__ Cb, float* __restrict__ Cf,
                                        const float* __restrict__ bias) {
  __shared__ bf16_t As[128 * 40];
  __shared__ bf16_t Bs[128 * 40];
  const int tid = threadIdx.x;
  const int w = tid >> 6, lane = tid & 63, quad = lane >> 4, l16 = lane & 15;
  const int sr = tid >> 2, sc = (tid & 3) << 3;
  const bf16_t* ga = A  + (size_t)(row0 + sr) * K + sc;
  const bf16_t* gb = Bt + (size_t)(n0  + sr) * K + sc;

  f32x4 acc[4][4];
#pragma unroll
  for (int i = 0; i < 4; ++i)
#pragma unroll
    for (int j = 0; j < 4; ++j) acc[i][j] = f32x4{0.f, 0.f, 0.f, 0.f};

  int4 ra0 = *(const int4*)(ga);
  int4 ra1 = *(const int4*)(ga + (size_t)64 * K);
  int4 rb0 = *(const int4*)(gb);
  int4 rb1 = *(const int4*)(gb + (size_t)64 * K);

  const int mrow = (w & 1) << 6, ncol = (w >> 1) << 6;
  const int KT = K >> 5;
  for (int kt = 0; kt < KT; ++kt) {
    __syncthreads();
    *(int4*)&As[sr * 40 + sc]        = ra0;
    *(int4*)&As[(sr + 64) * 40 + sc] = ra1;
    *(int4*)&Bs[sr * 40 + sc]        = rb0;
    *(int4*)&Bs[(sr + 64) * 40 + sc] = rb1;
    __syncthreads();
    if (kt + 1 < KT) {
      int k0 = (kt + 1) << 5;
      ra0 = *(const int4*)(ga + k0);
      ra1 = *(const int4*)(ga + (size_t)64 * K + k0);
      rb0 = *(const int4*)(gb + k0);
      rb1 = *(const int4*)(gb + (size_t)64 * K + k0);
    }
    bf16x8 af[4], bfr[4];
#pragma unroll
    for (int i = 0; i < 4; ++i)
      af[i] = *(const bf16x8*)&As[(mrow + i * 16 + l16) * 40 + quad * 8];
#pragma unroll
    for (int j = 0; j < 4; ++j)
      bfr[j] = *(const bf16x8*)&Bs[(ncol + j * 16 + l16) * 40 + quad * 8];
#pragma unroll
    for (int i = 0; i < 4; ++i)
#pragma unroll
      for (int j = 0; j < 4; ++j)
        acc[i][j] = MFMA16(af[i], bfr[j], acc[i][j]);
  }
#pragma unroll
  for (int i = 0; i < 4; ++i) {
    int row = row0 + mrow + i * 16 + quad * 4;
#pragma unroll
    for (int j = 0; j < 4; ++j) {
      int col = n0 + ncol + j * 16 + l16;
#pragma unroll
      for (int r = 0; r < 4; ++r) {
        if (Cf) Cf[(size_t)(row + r) * N + col] = acc[i][j][r] + bias[col];
        else    Cb[(size_t)(row + r) * N + col] = (bf16_t)(acc[i][j][r] * scale);
      }
    }
  }
}

__global__ __launch_bounds__(256, 2) void gemm_qkv_k(const bf16_t* __restrict__ xb,
                                                     const bf16_t* __restrict__ cb,
                                                     const bf16_t* __restrict__ WqT,
                                                     const bf16_t* __restrict__ WkT,
                                                     const bf16_t* __restrict__ WvT,
                                                     bf16_t* __restrict__ Qb,
                                                     bf16_t* __restrict__ Kb,
                                                     bf16_t* __restrict__ Vb) {
  int z = blockIdx.z;
  const bf16_t* A  = (z == 0) ? xb : cb;
  const bf16_t* Bt = (z == 0) ? WqT : (z == 1) ? WkT : WvT;
  bf16_t* C        = (z == 0) ? Qb  : (z == 1) ? Kb  : Vb;
  float scale      = (z == 0) ? QSCALE : 1.0f;
  gemm128(A, Bt, 1024, 512, blockIdx.y * 128, blockIdx.x * 128, scale, C, nullptr, nullptr);
}

__global__ __launch_bounds__(256, 2) void gemm_out_k(const bf16_t* __restrict__ AO,
                                                     const bf16_t* __restrict__ WoT,
                                                     const float* __restrict__ bo,
                                                     float* __restrict__ out) {
  gemm128(AO, WoT, 512, 1024, blockIdx.y * 128, blockIdx.x * 128, 1.0f, nullptr, out, bo);
}

// ---------- flash attention: transposed-S + global_load_lds staging ----------
// KsB: [key row][d] rows of 128 B, XOR-swizzled at 16 B granularity: physical
// chunk c of row r holds logical chunk c^(r&7). VsB: [d][key] rows of 256 B,
// physical chunk c holds logical c^(r&15). Per-lane GLOBAL address realizes
// the swizzle; LDS side is the mandatory base+lane*16 pattern.
__global__ __launch_bounds__(256, 3) void attn_k(const bf16_t* __restrict__ Qb,
                                                 const bf16_t* __restrict__ Kb,
                                                 const bf16_t* __restrict__ Vt,
                                                 bf16_t* __restrict__ AO) {
  const int tid = threadIdx.x;
  const int w = tid >> 6, lane = tid & 63, quad = lane >> 4, l16 = lane & 15;
  const int qt = blockIdx.x;        // 0..31
  const int bh = blockIdx.y;        // 0..15
  const int b = bh >> 3, h = bh & 7;

  __shared__ bf16_t KsB[128 * 64];  // 16 KB, swizzled
  __shared__ bf16_t VsB[64 * 128];  // 16 KB, swizzled
  __shared__ bf16_t Ps[64 * 136];   // 17 KB, padded (VALU-written)

  // Q B-frags: B[n=q(l16)][k=d(quad*8+j)] straight from global
  const int qrow = b * 2048 + qt * 64 + w * 16 + l16;
  const bf16_t* qptr = Qb + (size_t)qrow * INNER + h * DHEAD;
  bf16x8 bq[2];
  bq[0] = *(const bf16x8*)(qptr + quad * 8);
  bq[1] = *(const bf16x8*)(qptr + 32 + quad * 8);

  f32x4 o[4];
#pragma unroll
  for (int dt = 0; dt < 4; ++dt) o[dt] = f32x4{0.f, 0.f, 0.f, 0.f};
  float m_s = -__builtin_inff(), l_s = 0.f;

  const bf16_t* kbase  = Kb + ((size_t)b * 2048) * INNER + h * DHEAD;
  const bf16_t* vtbase = Vt + ((size_t)bh * 64) * 2048;

  // staging constants (see header comment)
  const int krow_c = w * 32 + (lane >> 3);              // + p*8
  const int kcol_c = ((lane & 7) ^ (lane >> 3)) << 3;   // logical col, elems
  const int vrow_c = w * 16 + (lane >> 4);              // + p*4
  bf16_t* ksl = &KsB[w * 2048];                         // wave-uniform LDS base
  bf16_t* vsl = &VsB[w * 2048];

  for (int kt = 0; kt < 16; ++kt) {
    __syncthreads();                 // prior iteration's LDS reads complete
#pragma unroll
    for (int p = 0; p < 4; ++p) {
      g2l(kbase + (size_t)(kt * 128 + krow_c + p * 8) * INNER + kcol_c,
          ksl + p * 512);
      int vlog = ((lane & 15) ^ ((p * 4 + (lane >> 4)) & 15)) << 3;
      g2l(vtbase + (size_t)(vrow_c + p * 4) * 2048 + kt * 128 + vlog,
          vsl + p * 512);
    }
    __syncthreads();                 // vmcnt drain + barrier: tiles visible

    // S^T tile [128 keys][16 q] per wave: A=K (m=key), B=Q (n=q)
    f32x4 s[8];
#pragma unroll
    for (int jt = 0; jt < 8; ++jt) s[jt] = f32x4{0.f, 0.f, 0.f, 0.f};
#pragma unroll
    for (int jt = 0; jt < 8; ++jt) {
#pragma unroll
      for (int ks = 0; ks < 2; ++ks) {
        int phys = ((ks * 4 + quad) ^ (l16 & 7)) << 3;
        bf16x8 ak = *(const bf16x8*)&KsB[(jt * 16 + l16) * 64 + phys];
        s[jt] = MFMA16(ak, bq[ks], s[jt]);
      }
    }

    // online softmax (exp2 domain); lane state is q-col l16; keys split
    // across quads -> 2 cross-lane reduction steps only
    float mx = -__builtin_inff();
#pragma unroll
    for (int jt = 0; jt < 8; ++jt) {
      float a = fmaxf(fmaxf(s[jt][0], s[jt][1]), fmaxf(s[jt][2], s[jt][3]));
      mx = fmaxf(mx, a);
    }
    mx = fmaxf(mx, __shfl_xor(mx, 16, 64));
    mx = fmaxf(mx, __shfl_xor(mx, 32, 64));
    float mnew = fmaxf(m_s, mx);
    float alpha = __builtin_amdgcn_exp2f(m_s - mnew);
    float rs = 0.f;
#pragma unroll
    for (int jt = 0; jt < 8; ++jt) {
#pragma unroll
      for (int r = 0; r < 4; ++r) {
        float p = __builtin_amdgcn_exp2f(s[jt][r] - mnew);
        s[jt][r] = p;
        rs += p;
      }
    }
    rs += __shfl_xor(rs, 16, 64);
    rs += __shfl_xor(rs, 32, 64);
    l_s = l_s * alpha + rs;
    m_s = mnew;
#pragma unroll
    for (int dt = 0; dt < 4; ++dt) o[dt] *= alpha;

    // P^T (C-layout) -> Ps[q][key], wave-private rows, packed 8 B writes
#pragma unroll
    for (int jt = 0; jt < 8; ++jt) {
      bf16x4 pk = { (bf16_t)s[jt][0], (bf16_t)s[jt][1],
                    (bf16_t)s[jt][2], (bf16_t)s[jt][3] };
      *(bf16x4*)&Ps[(w * 16 + l16) * 136 + jt * 16 + quad * 4] = pk;
    }

    // O^T += Vt . P^T : A=V^T (m=d), B=P^T (n=q)
#pragma unroll
    for (int kc = 0; kc < 4; ++kc) {
      bf16x8 bp = *(const bf16x8*)&Ps[(w * 16 + l16) * 136 + kc * 32 + quad * 8];
#pragma unroll
      for (int dt = 0; dt < 4; ++dt) {
        int phys = ((kc * 4 + quad) ^ l16) << 3;
        bf16x8 av = *(const bf16x8*)&VsB[(dt * 16 + l16) * 128 + phys];
        o[dt] = MFMA16(av, bp, o[dt]);
      }
    }
  }

  // epilogue: O^T[d][q] -> Ps as [q][d] (wave-private rows) -> coalesced store
  float inv = 1.0f / l_s;
#pragma unroll
  for (int dt = 0; dt < 4; ++dt) {
    bf16x4 ov = { (bf16_t)(o[dt][0] * inv), (bf16_t)(o[dt][1] * inv),
                  (bf16_t)(o[dt][2] * inv), (bf16_t)(o[dt][3] * inv) };
    *(bf16x4*)&Ps[(w * 16 + l16) * 136 + dt * 16 + quad * 4] = ov;
  }
  __syncthreads();
  {
    int sr = tid >> 2, sc = (tid & 3) << 4;
    int4 r0 = *(const int4*)&Ps[sr * 136 + sc];
    int4 r1 = *(const int4*)&Ps[sr * 136 + sc + 8];
    bf16_t* aout = AO + ((size_t)(b * 2048 + qt * 64 + sr)) * INNER + h * DHEAD + sc;
    *(int4*)aout       = r0;
    *(int4*)(aout + 8) = r1;
  }
}

// ---------- launch ----------
extern "C" void kernel_launch(void* const* d_in, const int* in_sizes, int n_in,
                              void* d_out, int out_size, void* d_ws, size_t ws_size,
                              hipStream_t stream) {
  const float* x   = (const float*)d_in[0];
  const float* ctx = (const float*)d_in[1];
  const float* Wq  = (const float*)d_in[2];
  const float* Wk  = (const float*)d_in[3];
  const float* Wv  = (const float*)d_in[4];
  const float* Wo  = (const float*)d_in[5];
  const float* bo  = (const float*)d_in[6];
  float* out = (float*)d_out;

  char* ws = (char*)d_ws;
  bf16_t* xb  = (bf16_t*)(ws + 0);          //  8 MB  [4096][1024]
  bf16_t* cb  = (bf16_t*)(ws + 8388608);    //  8 MB  [4096][1024]
  bf16_t* WqT = (bf16_t*)(ws + 16777216);   //  1 MB  [512][1024]
  bf16_t* WkT = (bf16_t*)(ws + 17825792);   //  1 MB
  bf16_t* WvT = (bf16_t*)(ws + 18874368);   //  1 MB
  bf16_t* WoT = (bf16_t*)(ws + 19922944);   //  1 MB  [1024][512]
  bf16_t* Qb  = (bf16_t*)(ws + 20971520);   //  4 MB  [4096][512] (pre-scaled)
  bf16_t* Kb  = (bf16_t*)(ws + 25165824);   //  4 MB
  bf16_t* Vb  = (bf16_t*)(ws + 29360128);   //  4 MB
  bf16_t* Vt  = (bf16_t*)(ws + 33554432);   //  4 MB  [16][64][2048]
  bf16_t* AO  = (bf16_t*)(ws + 37748736);   //  4 MB  [4096][512]

  cvt_k<<<dim3(4096, 2), 256, 0, stream>>>(x, ctx, xb, cb);
  wtrans_k<<<dim3(128, 4), 256, 0, stream>>>(Wq, Wk, Wv, Wo, WqT, WkT, WvT, WoT);
  gemm_qkv_k<<<dim3(4, 32, 3), 256, 0, stream>>>(xb, cb, WqT, WkT, WvT, Qb, Kb, Vb);
  vtrans_k<<<dim3(32, 16), 256, 0, stream>>>(Vb, Vt);
  attn_k<<<dim3(32, 16), 256, 0, stream>>>(Qb, Kb, Vt, AO);
  gemm_out_k<<<dim3(8, 32), 256, 0, stream>>>(AO, WoT, bo, out);
}

// Round 4
// 172.096 us; speedup vs baseline: 1.3986x; 1.0735x over previous
//
#include <hip/hip_runtime.h>
#include <math.h>

// ---------- types ----------
typedef __bf16 bf16_t;
typedef __bf16 bf16x8 __attribute__((ext_vector_type(8)));
typedef __bf16 bf16x4 __attribute__((ext_vector_type(4)));
typedef float  f32x4  __attribute__((ext_vector_type(4)));

#define MFMA16(a, b, c) __builtin_amdgcn_mfma_f32_16x16x32_bf16((a), (b), (c), 0, 0, 0)

// B=2, N=M=2048, QUERY_DIM=CONTEXT_DIM=1024, HEADS=8, DIM_HEAD=64, INNER=512
#define INNER   512
#define DHEAD   64
// SCALE * log2(e): Q pre-scaled so softmax runs in exp2 domain
#define QSCALE  0.18033688f

// direct HBM -> LDS, 16 B per lane; LDS dest = wave-uniform base + lane*16
__device__ __forceinline__ void g2l(const bf16_t* g, bf16_t* l) {
  __builtin_amdgcn_global_load_lds(
      (const __attribute__((address_space(1))) unsigned int*)g,
      (__attribute__((address_space(3))) unsigned int*)l, 16, 0, 0);
}

// ---------- fused preprocessing ----------
// bx < 8192 : fp32->bf16 convert (x: 0..4095, ctx: 4096..8191)
// bx >= 8192: weight transpose+convert, 4 matrices x 128 tiles
__global__ __launch_bounds__(256) void pre_k(const float* __restrict__ x,
                                             const float* __restrict__ ctx,
                                             const float* __restrict__ Wq,
                                             const float* __restrict__ Wk,
                                             const float* __restrict__ Wv,
                                             const float* __restrict__ Wo,
                                             bf16_t* __restrict__ xb,
                                             bf16_t* __restrict__ cb,
                                             bf16_t* __restrict__ WqT,
                                             bf16_t* __restrict__ WkT,
                                             bf16_t* __restrict__ WvT,
                                             bf16_t* __restrict__ WoT) {
  __shared__ float tile[64][65];
  int bx = blockIdx.x;
  if (bx < 8192) {
    const float* in = (bx >= 4096) ? ctx : x;
    bf16_t* out     = (bx >= 4096) ? cb  : xb;
    int i = (bx & 4095) * 256 + threadIdx.x;
    float4 f = ((const float4*)in)[i];
    bf16x4 v = { (bf16_t)f.x, (bf16_t)f.y, (bf16_t)f.z, (bf16_t)f.w };
    ((bf16x4*)out)[i] = v;
    return;
  }
  int t = bx - 8192;
  int z = t >> 7, bid = t & 127;
  const float* W; bf16_t* WT; int K, N;
  if (z == 0)      { W = Wq; WT = WqT; K = 1024; N = 512; }
  else if (z == 1) { W = Wk; WT = WkT; K = 1024; N = 512; }
  else if (z == 2) { W = Wv; WT = WvT; K = 1024; N = 512; }
  else             { W = Wo; WT = WoT; K = 512;  N = 1024; }
  int tK = K >> 6;
  int kt = bid % tK, nt = bid / tK;
  int k0 = kt << 6, n0 = nt << 6;
  for (int idx = threadIdx.x; idx < 4096; idx += 256) {
    int r = idx >> 6, c = idx & 63;
    tile[r][c] = W[(size_t)(k0 + r) * N + n0 + c];
  }
  __syncthreads();
  for (int idx = threadIdx.x; idx < 4096; idx += 256) {
    int r = idx >> 6, c = idx & 63;
    WT[(size_t)(n0 + r) * K + k0 + c] = (bf16_t)tile[c][r];
  }
}

// ---------- 128x128 GEMM, m97-structure: global_load_lds staging, BK=32 ----------
// LDS tiles 128x32 bf16 unpadded; 16B chunks XOR-swizzled: phys = log ^ ((row>>1)&3)
// -> b128 reads are 2-way bank-aliased only (free, m136).
// mode 0: bf16 out with scale; mode 1: f32 out + bias; mode 2: scatter to Vt.
__device__ __forceinline__ void gemm128(const bf16_t* __restrict__ A,
                                        const bf16_t* __restrict__ Bt,
                                        int K, int N, int row0, int n0,
                                        int mode, float scale,
                                        bf16_t* __restrict__ Cb,
                                        float* __restrict__ Cf,
                                        const float* __restrict__ bias) {
  __shared__ bf16_t As[128 * 32];
  __shared__ bf16_t Bs[128 * 32];
  const int tid = threadIdx.x;
  const int w = tid >> 6, lane = tid & 63, quad = lane >> 4, l16 = lane & 15;

  // staging: wave w covers rows w*32 + p*16 + (lane>>2); phys chunk = lane&3,
  // so the GLOBAL column supplies logical chunk = (lane&3) ^ ((lane>>3)&3)
  const int srow = lane >> 2;
  const int logc = (lane & 3) ^ ((lane >> 3) & 3);
  const bf16_t* gaw = A  + (size_t)(row0 + w * 32 + srow) * K + logc * 8;
  const bf16_t* gbw = Bt + (size_t)(n0   + w * 32 + srow) * K + logc * 8;
  bf16_t* lA = As + w * 1024;   // + p*512
  bf16_t* lB = Bs + w * 1024;

  f32x4 acc[4][4];
#pragma unroll
  for (int i = 0; i < 4; ++i)
#pragma unroll
    for (int j = 0; j < 4; ++j) acc[i][j] = f32x4{0.f, 0.f, 0.f, 0.f};

  const int mrow = (w & 1) << 6, ncol = (w >> 1) << 6;
  const int rphys = (quad ^ ((l16 >> 1) & 3)) << 3;  // lane-constant chunk offset
  const int KT = K >> 5;

  for (int kc = 0; kc < KT; ++kc) {
    __syncthreads();
    g2l(gaw + kc * 32,                   lA);
    g2l(gaw + (size_t)16 * K + kc * 32,  lA + 512);
    g2l(gbw + kc * 32,                   lB);
    g2l(gbw + (size_t)16 * K + kc * 32,  lB + 512);
    __syncthreads();
    bf16x8 af[4], bfr[4];
#pragma unroll
    for (int i = 0; i < 4; ++i)
      af[i] = *(const bf16x8*)&As[(mrow + i * 16 + l16) * 32 + rphys];
#pragma unroll
    for (int j = 0; j < 4; ++j)
      bfr[j] = *(const bf16x8*)&Bs[(ncol + j * 16 + l16) * 32 + rphys];
#pragma unroll
    for (int i = 0; i < 4; ++i)
#pragma unroll
      for (int j = 0; j < 4; ++j)
        acc[i][j] = MFMA16(af[i], bfr[j], acc[i][j]);
  }

  // epilogue: C/D layout col=l16, row=quad*4+reg
#pragma unroll
  for (int i = 0; i < 4; ++i) {
    int row = row0 + mrow + i * 16 + quad * 4;
#pragma unroll
    for (int j = 0; j < 4; ++j) {
      int col = n0 + ncol + j * 16 + l16;
      if (mode == 2) {
        // scatter to Vt[bh=b*8+h][d][key]: row -> (b,key), col -> (h,d)
        int bb = row >> 11, key = row & 2047;
        int hh = col >> 6,  d   = col & 63;
        bf16x4 v = { (bf16_t)acc[i][j][0], (bf16_t)acc[i][j][1],
                     (bf16_t)acc[i][j][2], (bf16_t)acc[i][j][3] };
        *(bf16x4*)&Cb[((size_t)((bb * 8 + hh) * 64 + d)) * 2048 + key] = v;
      } else {
#pragma unroll
        for (int r = 0; r < 4; ++r) {
          if (mode == 1) Cf[(size_t)(row + r) * N + col] = acc[i][j][r] + bias[col];
          else           Cb[(size_t)(row + r) * N + col] = (bf16_t)(acc[i][j][r] * scale);
        }
      }
    }
  }
}

__global__ __launch_bounds__(256, 2) void gemm_qkv_k(const bf16_t* __restrict__ xb,
                                                     const bf16_t* __restrict__ cb,
                                                     const bf16_t* __restrict__ WqT,
                                                     const bf16_t* __restrict__ WkT,
                                                     const bf16_t* __restrict__ WvT,
                                                     bf16_t* __restrict__ Qb,
                                                     bf16_t* __restrict__ Kb,
                                                     bf16_t* __restrict__ Vt) {
  int z = blockIdx.z;
  const bf16_t* A  = (z == 0) ? xb  : cb;
  const bf16_t* Bt = (z == 0) ? WqT : (z == 1) ? WkT : WvT;
  bf16_t* C        = (z == 0) ? Qb  : (z == 1) ? Kb  : Vt;
  int mode         = (z == 2) ? 2 : 0;
  float scale      = (z == 0) ? QSCALE : 1.0f;
  gemm128(A, Bt, 1024, 512, blockIdx.y * 128, blockIdx.x * 128, mode, scale,
          C, nullptr, nullptr);
}

__global__ __launch_bounds__(256, 2) void gemm_out_k(const bf16_t* __restrict__ AO,
                                                     const bf16_t* __restrict__ WoT,
                                                     const float* __restrict__ bo,
                                                     float* __restrict__ out) {
  gemm128(AO, WoT, 512, 1024, blockIdx.y * 128, blockIdx.x * 128, 1, 1.0f,
          nullptr, out, bo);
}

// ---------- flash attention: transposed-S, pipelined staging ----------
// K double-buffered (2x16 KB), V single (16 KB), Ps padded (17 KB) = 65.4 KB
// -> 2 blocks/CU. Loads for K(kt+1), V(kt) are issued after the top barrier
// and drained at the mid barrier; S+softmax (~500 cyc) hides their latency.
__global__ __launch_bounds__(256, 2) void attn_k(const bf16_t* __restrict__ Qb,
                                                 const bf16_t* __restrict__ Kb,
                                                 const bf16_t* __restrict__ Vt,
                                                 bf16_t* __restrict__ AO) {
  const int tid = threadIdx.x;
  const int w = tid >> 6, lane = tid & 63, quad = lane >> 4, l16 = lane & 15;
  const int qt = blockIdx.x;        // 0..31
  const int bh = blockIdx.y;        // 0..15
  const int b = bh >> 3, h = bh & 7;

  __shared__ bf16_t Ks[2 * 128 * 64];  // [buf][key][d] rows 128 B, swizzle r&7
  __shared__ bf16_t Vs[64 * 128];      // [d][key]      rows 256 B, swizzle r&15
  __shared__ bf16_t Ps[64 * 136];      // [q][key]      padded, wave-private rows

  // Q B-frags: B[n=q(l16)][k=d(quad*8+j)] straight from global
  const int qrow = b * 2048 + qt * 64 + w * 16 + l16;
  const bf16_t* qptr = Qb + (size_t)qrow * INNER + h * DHEAD;
  bf16x8 bq[2];
  bq[0] = *(const bf16x8*)(qptr + quad * 8);
  bq[1] = *(const bf16x8*)(qptr + 32 + quad * 8);

  f32x4 o[4];
#pragma unroll
  for (int dt = 0; dt < 4; ++dt) o[dt] = f32x4{0.f, 0.f, 0.f, 0.f};
  float m_s = -__builtin_inff(), l_s = 0.f;

  const bf16_t* kbase  = Kb + ((size_t)b * 2048) * INNER + h * DHEAD;
  const bf16_t* vtbase = Vt + ((size_t)bh * 64) * 2048;

  const int krow = lane >> 3;                    // + p*8, within wave's 32 rows
  const int kcol = ((lane & 7) ^ (lane >> 3)) << 3;
  const int vrow = lane >> 4;                    // + p*4

  // prologue: K tile 0 -> buf 0
#pragma unroll
  for (int p = 0; p < 4; ++p)
    g2l(kbase + (size_t)(w * 32 + p * 8 + krow) * INNER + kcol,
        &Ks[w * 2048 + p * 512]);

  for (int kt = 0; kt < 16; ++kt) {
    const int cur = (kt & 1) * 8192, nxt = ((kt + 1) & 1) * 8192;
    __syncthreads();   // drains K(kt) [+anything older]; joins all waves
    if (kt < 16 - 1) {
#pragma unroll
      for (int p = 0; p < 4; ++p)
        g2l(kbase + (size_t)((kt + 1) * 128 + w * 32 + p * 8 + krow) * INNER + kcol,
            &Ks[nxt + w * 2048 + p * 512]);
    }
#pragma unroll
    for (int p = 0; p < 4; ++p) {
      int vlog = ((lane & 15) ^ ((p * 4 + vrow) & 15)) << 3;
      g2l(vtbase + (size_t)(w * 16 + p * 4 + vrow) * 2048 + kt * 128 + vlog,
          &Vs[w * 2048 + p * 512]);
    }

    // S^T tile [128 keys][16 q] per wave from K(cur)
    f32x4 s[8];
#pragma unroll
    for (int jt = 0; jt < 8; ++jt) s[jt] = f32x4{0.f, 0.f, 0.f, 0.f};
#pragma unroll
    for (int jt = 0; jt < 8; ++jt) {
#pragma unroll
      for (int ks = 0; ks < 2; ++ks) {
        int phys = ((ks * 4 + quad) ^ (l16 & 7)) << 3;
        bf16x8 ak = *(const bf16x8*)&Ks[cur + (jt * 16 + l16) * 64 + phys];
        s[jt] = MFMA16(ak, bq[ks], s[jt]);
      }
    }

    // online softmax (exp2 domain); per-lane scalar state for q-col l16
    float mx = -__builtin_inff();
#pragma unroll
    for (int jt = 0; jt < 8; ++jt) {
      float a = fmaxf(fmaxf(s[jt][0], s[jt][1]), fmaxf(s[jt][2], s[jt][3]));
      mx = fmaxf(mx, a);
    }
    mx = fmaxf(mx, __shfl_xor(mx, 16, 64));
    mx = fmaxf(mx, __shfl_xor(mx, 32, 64));
    float mnew = fmaxf(m_s, mx);
    float alpha = __builtin_amdgcn_exp2f(m_s - mnew);
    float rs = 0.f;
#pragma unroll
    for (int jt = 0; jt < 8; ++jt) {
#pragma unroll
      for (int r = 0; r < 4; ++r) {
        float p = __builtin_amdgcn_exp2f(s[jt][r] - mnew);
        s[jt][r] = p;
        rs += p;
      }
    }
    rs += __shfl_xor(rs, 16, 64);
    rs += __shfl_xor(rs, 32, 64);
    l_s = l_s * alpha + rs;
    m_s = mnew;
#pragma unroll
    for (int dt = 0; dt < 4; ++dt) o[dt] *= alpha;

    // P^T (C-layout) -> Ps[q][key], wave-private rows, packed 8 B writes
#pragma unroll
    for (int jt = 0; jt < 8; ++jt) {
      bf16x4 pk = { (bf16_t)s[jt][0], (bf16_t)s[jt][1],
                    (bf16_t)s[jt][2], (bf16_t)s[jt][3] };
      *(bf16x4*)&Ps[(w * 16 + l16) * 136 + jt * 16 + quad * 4] = pk;
    }

    __syncthreads();   // drains V(kt) (K(kt+1) rides along, already landed)

    // O^T += Vt . P^T
#pragma unroll
    for (int kc = 0; kc < 4; ++kc) {
      bf16x8 bp = *(const bf16x8*)&Ps[(w * 16 + l16) * 136 + kc * 32 + quad * 8];
#pragma unroll
      for (int dt = 0; dt < 4; ++dt) {
        int phys = ((kc * 4 + quad) ^ l16) << 3;
        bf16x8 av = *(const bf16x8*)&Vs[(dt * 16 + l16) * 128 + phys];
        o[dt] = MFMA16(av, bp, o[dt]);
      }
    }
  }

  // epilogue: O^T[d][q] -> Ps as [q][d] (wave-private rows) -> coalesced store
  float inv = 1.0f / l_s;
#pragma unroll
  for (int dt = 0; dt < 4; ++dt) {
    bf16x4 ov = { (bf16_t)(o[dt][0] * inv), (bf16_t)(o[dt][1] * inv),
                  (bf16_t)(o[dt][2] * inv), (bf16_t)(o[dt][3] * inv) };
    *(bf16x4*)&Ps[(w * 16 + l16) * 136 + dt * 16 + quad * 4] = ov;
  }
  __syncthreads();
  {
    int sr = tid >> 2, sc = (tid & 3) << 4;
    int4 r0 = *(const int4*)&Ps[sr * 136 + sc];
    int4 r1 = *(const int4*)&Ps[sr * 136 + sc + 8];
    bf16_t* aout = AO + ((size_t)(b * 2048 + qt * 64 + sr)) * INNER + h * DHEAD + sc;
    *(int4*)aout       = r0;
    *(int4*)(aout + 8) = r1;
  }
}

// ---------- launch ----------
extern "C" void kernel_launch(void* const* d_in, const int* in_sizes, int n_in,
                              void* d_out, int out_size, void* d_ws, size_t ws_size,
                              hipStream_t stream) {
  const float* x   = (const float*)d_in[0];
  const float* ctx = (const float*)d_in[1];
  const float* Wq  = (const float*)d_in[2];
  const float* Wk  = (const float*)d_in[3];
  const float* Wv  = (const float*)d_in[4];
  const float* Wo  = (const float*)d_in[5];
  const float* bo  = (const float*)d_in[6];
  float* out = (float*)d_out;

  char* ws = (char*)d_ws;
  const size_t MB = 1048576;
  bf16_t* xb  = (bf16_t*)(ws + 0 * MB);    //  8 MB  [4096][1024]
  bf16_t* cb  = (bf16_t*)(ws + 8 * MB);    //  8 MB  [4096][1024]
  bf16_t* WqT = (bf16_t*)(ws + 16 * MB);   //  1 MB  [512][1024]
  bf16_t* WkT = (bf16_t*)(ws + 17 * MB);   //  1 MB
  bf16_t* WvT = (bf16_t*)(ws + 18 * MB);   //  1 MB
  bf16_t* WoT = (bf16_t*)(ws + 19 * MB);   //  1 MB  [1024][512]
  bf16_t* Qb  = (bf16_t*)(ws + 20 * MB);   //  4 MB  [4096][512] (pre-scaled)
  bf16_t* Kb  = (bf16_t*)(ws + 24 * MB);   //  4 MB  [4096][512]
  bf16_t* Vt  = (bf16_t*)(ws + 28 * MB);   //  4 MB  [16][64][2048]
  bf16_t* AO  = (bf16_t*)(ws + 32 * MB);   //  4 MB  [4096][512]

  pre_k<<<8704, 256, 0, stream>>>(x, ctx, Wq, Wk, Wv, Wo, xb, cb, WqT, WkT, WvT, WoT);
  gemm_qkv_k<<<dim3(4, 32, 3), 256, 0, stream>>>(xb, cb, WqT, WkT, WvT, Qb, Kb, Vt);
  attn_k<<<dim3(32, 16), 256, 0, stream>>>(Qb, Kb, Vt, AO);
  gemm_out_k<<<dim3(8, 32), 256, 0, stream>>>(AO, WoT, bo, out);
}